// Round 6
// baseline (151.845 us; speedup 1.0000x reference)
//
#include <hip/hip_runtime.h>

typedef __attribute__((ext_vector_type(8))) _Float16 f16x8;
typedef __attribute__((ext_vector_type(4))) float f32x4;

static constexpr int TT = 100, BB = 256, DD = 784, HH = 256;
static constexpr int MM = TT * BB;      // 25600
static constexpr int K1PAD = 800;       // 784 -> 25*32
static constexpr int N2PAD = 896;       // 784 -> 7*128
static constexpr float MIDSC = 2048.0f, INVMID = 1.0f / 2048.0f;

__device__ __forceinline__ unsigned short f2h(float x) {
  _Float16 h = (_Float16)x;
  return *(unsigned short*)&h;
}
__device__ __forceinline__ float h2f(unsigned short u) {
  _Float16 h = *(_Float16*)&u;
  return (float)h;
}
__device__ __forceinline__ void glds16(const void* g, void* l) {
  __builtin_amdgcn_global_load_lds(
      (const __attribute__((address_space(1))) unsigned int*)g,
      (__attribute__((address_space(3))) unsigned int*)l, 16, 0, 0);
}

// Split fp32 W[N][K] into 2 f16 planes [Npad][Kpad]:
//   p0 = f16(w),  p1 = f16((w - p0) * 2048);  reconstruct p0 + p1/2048 (~2^-22 rel).
__global__ __launch_bounds__(256)
void split_w(const float* __restrict__ W, unsigned short* __restrict__ Ws,
             int N, int K, int Npad, int Kpad) {
  int idx = blockIdx.x * 256 + threadIdx.x;
  int total = Npad * Kpad;
  if (idx >= total) return;
  int row = idx / Kpad, col = idx - row * Kpad;
  float w = (row < N && col < K) ? W[row * K + col] : 0.0f;
  unsigned short h0 = f2h(w);
  float r = (w - h2f(h0)) * MIDSC;
  Ws[idx] = h0;
  Ws[total + idx] = f2h(r);
}

// Binary fp32 X[rows][784] -> f16 Xh[rows][800] (zero-padded cols), 8 elems/thread.
__global__ __launch_bounds__(256)
void conv_x(const float* __restrict__ x, unsigned short* __restrict__ xh, int rows) {
  const int OC = K1PAD / 8;                 // 100 octets per row
  int idx = blockIdx.x * 256 + threadIdx.x;
  if (idx >= rows * OC) return;
  int row = idx / OC, o = idx - row * OC;
  uint4 v = {0u, 0u, 0u, 0u};
  if (o < DD / 8) {                         // 98 data octets (784 = 98*8)
    const float4 f0 = *(const float4*)&x[(size_t)row * DD + o * 8];
    const float4 f1 = *(const float4*)&x[(size_t)row * DD + o * 8 + 4];
    const unsigned ONE = 0x3C00u;           // f16 1.0
    v.x = (f0.x != 0.f ? ONE : 0u) | (f0.y != 0.f ? ONE << 16 : 0u);
    v.y = (f0.z != 0.f ? ONE : 0u) | (f0.w != 0.f ? ONE << 16 : 0u);
    v.z = (f1.x != 0.f ? ONE : 0u) | (f1.y != 0.f ? ONE << 16 : 0u);
    v.w = (f1.z != 0.f ? ONE : 0u) | (f1.w != 0.f ? ONE << 16 : 0u);
  }
  *(uint4*)&xh[(size_t)row * K1PAD + o * 8] = v;
}

// C[M,N] = Ah[M,Kpad] @ (p0 + p1/2048 of B)^T + bias[N]
// BM=BN=128, BK=32, 4 waves 2x2 (64x64), mfma_f32_16x16x32_f16, dual accumulators.
// TRIPLE-buffered LDS, prefetch distance 2, counted vmcnt (T3/T4): the loop never
// drains vmcnt to 0; each step waits only for the tile it is about to need next.
// XOR-swizzled LDS (16B chunks): phys_chunk = log_chunk ^ (((row&15)>>1)&3);
// glds dest stays LINEAR, swizzle applied by permuting each lane's GLOBAL source chunk.
// Requires nkb >= 2. All 6 glds per wave per step are unconditional.
template<bool GUARD_NST>
__global__ __launch_bounds__(256, 2)
void gemm_pipe(const unsigned short* __restrict__ Ah,
               const unsigned short* __restrict__ Bs, size_t planeStride,
               const float* __restrict__ bias, float* __restrict__ C,
               int M, int N, int Kpad) {
  __shared__ unsigned short Asm[3][128 * 32];      // 24 KB
  __shared__ unsigned short Bsm[3][2][128 * 32];   // 48 KB
  const int tid = threadIdx.x;
  const int bm = blockIdx.x * 128, bn = blockIdx.y * 128;
  const int wid = tid >> 6, lane = tid & 63;
  const int wr = (wid >> 1) * 64, wc = (wid & 1) * 64;
  const int l15 = lane & 15, l4 = lane >> 4;

  f32x4 acc[2][4][4];
#pragma unroll
  for (int s = 0; s < 2; ++s)
#pragma unroll
    for (int m = 0; m < 4; ++m)
#pragma unroll
      for (int n = 0; n < 4; ++n) acc[s][m][n] = (f32x4){0.f, 0.f, 0.f, 0.f};

  // glds: wave wid stages tile rows [wid*32, wid*32+32), two 16-row issues each.
  // Lane fills phys row (lane>>2), phys chunk (lane&3); source content is the
  // inverse-swizzled logical chunk (lane&3)^((lane>>3)&3).
  const int rl = wid * 32 + (lane >> 2);
  const int ce = ((lane & 3) ^ ((lane >> 3) & 3)) * 8;

  const unsigned short* asrc[2];
#pragma unroll
  for (int i = 0; i < 2; ++i)
    asrc[i] = Ah + (size_t)(bm + rl + i * 16) * Kpad + ce;
  const unsigned short* bsrc[2][2];
#pragma unroll
  for (int s = 0; s < 2; ++s)
#pragma unroll
    for (int i = 0; i < 2; ++i)
      bsrc[s][i] = Bs + (size_t)s * planeStride + (size_t)(bn + rl + i * 16) * Kpad + ce;

  // fragment reads: row = base + l15, logical chunk = l4 -> phys chunk swizzled
  const int rdsw = (l4 ^ ((l15 >> 1) & 3)) * 8;

  const int nkb = Kpad / 32;

  auto stage = [&](int t) {
    const int k0 = t * 32;
    const int bi = t % 3;
    glds16(asrc[0] + k0, &Asm[bi][(wid * 32) * 32]);
    glds16(asrc[1] + k0, &Asm[bi][(wid * 32 + 16) * 32]);
#pragma unroll
    for (int s = 0; s < 2; ++s) {
      glds16(bsrc[s][0] + k0, &Bsm[bi][s][(wid * 32) * 32]);
      glds16(bsrc[s][1] + k0, &Bsm[bi][s][(wid * 32 + 16) * 32]);
    }
  };

  // prologue: tiles 0 and 1 in flight; wait tile 0 (keep tile 1 flying)
  stage(0);
  stage(1);
  asm volatile("s_waitcnt vmcnt(6)" ::: "memory");
  __builtin_amdgcn_s_barrier();
  __builtin_amdgcn_sched_barrier(0);

  for (int kb = 0; kb < nkb; ++kb) {
    if (kb + 2 < nkb) stage(kb + 2);     // into buf[(kb+2)%3] = buf[(kb-1)%3], freed at barrier(kb-1)
    const int cur = kb % 3;

    f16x8 afr[4];
#pragma unroll
    for (int m = 0; m < 4; ++m)
      afr[m] = *(const f16x8*)&Asm[cur][(wr + m * 16 + l15) * 32 + rdsw];
#pragma unroll
    for (int s = 0; s < 2; ++s) {
      f16x8 bfr[4];
#pragma unroll
      for (int n = 0; n < 4; ++n)
        bfr[n] = *(const f16x8*)&Bsm[cur][s][(wc + n * 16 + l15) * 32 + rdsw];
#pragma unroll
      for (int m = 0; m < 4; ++m)
#pragma unroll
        for (int n = 0; n < 4; ++n)
          acc[s][m][n] = __builtin_amdgcn_mfma_f32_16x16x32_f16(afr[m], bfr[n], acc[s][m][n], 0, 0, 0);
    }

    __builtin_amdgcn_sched_barrier(0);   // pin MFMAs/ds_reads above the wait
    if (kb + 2 < nkb)
      asm volatile("s_waitcnt vmcnt(6)" ::: "memory");   // tile kb+1 landed; kb+2 stays in flight
    else
      asm volatile("s_waitcnt vmcnt(0)" ::: "memory");   // tail: drain last tile
    __builtin_amdgcn_s_barrier();
    __builtin_amdgcn_sched_barrier(0);
  }

#pragma unroll
  for (int m = 0; m < 4; ++m)
#pragma unroll
    for (int n = 0; n < 4; ++n) {
      const int col = bn + wc + n * 16 + l15;
      if (GUARD_NST && col >= N) continue;
      const float bv = bias[col];
#pragma unroll
      for (int r = 0; r < 4; ++r) {
        const int row = bm + wr + m * 16 + l4 * 4 + r;
        C[(size_t)row * N + col] = fmaf(acc[1][m][n][r], INVMID, acc[0][m][n][r]) + bv;
      }
    }
}

__device__ __forceinline__ float lif_step(float& mem, float c) {
  const float reset = (mem > 1.0f) ? 1.0f : 0.0f;
  mem = __fsub_rn(__fadd_rn(__fmul_rn(0.9f, mem), c), reset);
  return (mem > 1.0f) ? 1.0f : 0.0f;
}

// fp32 currents -> f16 spikes, 4 elems/thread
__global__ __launch_bounds__(256)
void lif_scan_h4(const float4* __restrict__ cur, uint2* __restrict__ spk,
                 int NE4, int nt) {
  const int tid = blockIdx.x * 256 + threadIdx.x;
  float4 mem = make_float4(0.f, 0.f, 0.f, 0.f);
#pragma unroll 4
  for (int t = 0; t < nt; ++t) {
    const float4 c = cur[(size_t)t * NE4 + tid];
    unsigned s0 = lif_step(mem.x, c.x) != 0.f ? 0x3C00u : 0u;
    unsigned s1 = lif_step(mem.y, c.y) != 0.f ? 0x3C00u : 0u;
    unsigned s2 = lif_step(mem.z, c.z) != 0.f ? 0x3C00u : 0u;
    unsigned s3 = lif_step(mem.w, c.w) != 0.f ? 0x3C00u : 0u;
    uint2 o;
    o.x = s0 | (s1 << 16);
    o.y = s2 | (s3 << 16);
    spk[(size_t)t * NE4 + tid] = o;
  }
}

// fp32 in-place, 4 elems/thread
__global__ __launch_bounds__(256)
void lif_scan_f32x4(float4* buf, int NE4, int nt) {
  const int tid = blockIdx.x * 256 + threadIdx.x;
  float4 mem = make_float4(0.f, 0.f, 0.f, 0.f);
#pragma unroll 4
  for (int t = 0; t < nt; ++t) {
    const float4 c = buf[(size_t)t * NE4 + tid];
    float4 o;
    o.x = lif_step(mem.x, c.x);
    o.y = lif_step(mem.y, c.y);
    o.z = lif_step(mem.z, c.z);
    o.w = lif_step(mem.w, c.w);
    buf[(size_t)t * NE4 + tid] = o;
  }
}

extern "C" void kernel_launch(void* const* d_in, const int* in_sizes, int n_in,
                              void* d_out, int out_size, void* d_ws, size_t ws_size,
                              hipStream_t stream) {
  const float* x  = (const float*)d_in[0];
  const float* W1 = (const float*)d_in[1];
  const float* b1 = (const float*)d_in[2];
  const float* W2 = (const float*)d_in[3];
  const float* b2 = (const float*)d_in[4];
  float* out = (float*)d_out;

  const size_t w1s_elems = (size_t)2 * HH * K1PAD;
  const size_t w2s_elems = (size_t)2 * N2PAD * HH;
  unsigned short* W1s = (unsigned short*)d_ws;
  unsigned short* W2s = W1s + w1s_elems;
  float* cur1 = (float*)(W2s + w2s_elems);
  unsigned short* spk1 = (unsigned short*)(cur1 + (size_t)MM * HH);
  // Xh (f16 [MM][800] = 41 MB) lives in d_out (80 MB): dead before GEMM2 writes d_out.
  unsigned short* Xh = (unsigned short*)d_out;

  dim3 blk(256);

  split_w<<<dim3((HH * K1PAD + 255) / 256), blk, 0, stream>>>(W1, W1s, HH, DD, HH, K1PAD);
  split_w<<<dim3((N2PAD * HH + 255) / 256), blk, 0, stream>>>(W2, W2s, DD, HH, N2PAD, HH);
  conv_x<<<dim3((MM * (K1PAD / 8) + 255) / 256), blk, 0, stream>>>(x, Xh, MM);

  // layer 1: cur1[M,256] = Xh[M,800] @ W1s^T + b1
  gemm_pipe<false><<<dim3(MM / 128, HH / 128), blk, 0, stream>>>(
      Xh, W1s, (size_t)HH * K1PAD, b1, cur1, MM, HH, K1PAD);

  lif_scan_h4<<<dim3((BB * HH / 4) / 256), blk, 0, stream>>>(
      (const float4*)cur1, (uint2*)spk1, BB * HH / 4, TT);

  // layer 2: out[M,784] = spk1[M,256] @ W2s^T + b2  (overwrites Xh scratch)
  gemm_pipe<true><<<dim3(MM / 128, N2PAD / 128), blk, 0, stream>>>(
      spk1, W2s, (size_t)N2PAD * HH, b2, out, MM, DD, HH);

  lif_scan_f32x4<<<dim3((BB * DD / 4) / 256), blk, 0, stream>>>(
      (float4*)out, BB * DD / 4, TT);
}

// Round 7
// 113.554 us; speedup vs baseline: 1.3372x; 1.3372x over previous
//
#include <hip/hip_runtime.h>

typedef __attribute__((ext_vector_type(8))) _Float16 f16x8;
typedef __attribute__((ext_vector_type(4))) float f32x4;

static constexpr int TT = 100, BB = 256, DD = 784, HH = 256;
static constexpr int MM = TT * BB;      // 25600
static constexpr int K1PAD = 800;       // 784 -> 25*32
static constexpr int DPAD = 832;        // 784 -> 13*64
static constexpr float MIDSC = 2048.0f, INVMID = 1.0f / 2048.0f;

__device__ __forceinline__ unsigned short f2h(float x) {
  _Float16 h = (_Float16)x;
  return *(unsigned short*)&h;
}
__device__ __forceinline__ float h2f(unsigned short u) {
  _Float16 h = *(_Float16*)&u;
  return (float)h;
}
__device__ __forceinline__ void glds16(const void* g, void* l) {
  __builtin_amdgcn_global_load_lds(
      (const __attribute__((address_space(1))) unsigned int*)g,
      (__attribute__((address_space(3))) unsigned int*)l, 16, 0, 0);
}

// Split fp32 W[N][K] into 2 f16 planes [Npad][Kpad]:
//   p0 = f16(w), p1 = f16((w - p0) * 2048); reconstruct p0 + p1/2048 (~2^-22 rel).
__global__ __launch_bounds__(256)
void split_w(const float* __restrict__ W, unsigned short* __restrict__ Ws,
             int N, int K, int Npad, int Kpad) {
  int idx = blockIdx.x * 256 + threadIdx.x;
  int total = Npad * Kpad;
  if (idx >= total) return;
  int row = idx / Kpad, col = idx - row * Kpad;
  float w = (row < N && col < K) ? W[row * K + col] : 0.0f;
  unsigned short h0 = f2h(w);
  float r = (w - h2f(h0)) * MIDSC;
  Ws[idx] = h0;
  Ws[total + idx] = f2h(r);
}

// Layer-1 GEMM: cur1[M,256] = X[M,784](binary fp32) @ (2-plane f16 W1)^T + b1.
// BM=BN=128, BK=32, 4 waves 2x2, mfma_f32_16x16x32_f16, dual plane accumulators.
// B: glds triple-buffer, counted vmcnt(4) (depth-2, never drained mid-loop).
// A: fp32 binary -> f16 {0,1} packed in regs, ds_written one step ahead (dbuf).
// XOR-swizzled LDS (16B chunks): phys_chunk = log_chunk ^ (((row&15)>>1)&3).
__global__ __launch_bounds__(256, 2)
void gemm1(const float* __restrict__ X, const unsigned short* __restrict__ Bs,
           const float* __restrict__ bias, float* __restrict__ C) {
  constexpr int Kpad = K1PAD, nkb = Kpad / 32;   // 25
  __shared__ unsigned short Asm[2][128 * 32];      // 16 KB
  __shared__ unsigned short Bsm[3][2][128 * 32];   // 48 KB
  const int tid = threadIdx.x;
  const int bm = blockIdx.x * 128, bn = blockIdx.y * 128;
  const int wid = tid >> 6, lane = tid & 63;
  const int wr = (wid >> 1) * 64, wc = (wid & 1) * 64;
  const int l15 = lane & 15, l4 = lane >> 4;

  f32x4 acc[2][4][4];
#pragma unroll
  for (int s = 0; s < 2; ++s)
#pragma unroll
    for (int m = 0; m < 4; ++m)
#pragma unroll
      for (int n = 0; n < 4; ++n) acc[s][m][n] = (f32x4){0.f, 0.f, 0.f, 0.f};

  // B glds geometry (pre-swizzled global source chunk, linear LDS dest)
  const int rl = wid * 32 + (lane >> 2);
  const int ce = ((lane & 3) ^ ((lane >> 3) & 3)) * 8;
  const size_t pstr = (size_t)HH * Kpad;
  const unsigned short* bsrc0 = Bs + (size_t)(bn + rl) * Kpad + ce;
  const unsigned short* bsrc1 = Bs + (size_t)(bn + rl + 16) * Kpad + ce;

  // fragment read swizzle
  const int rdsw = (l4 ^ ((l15 >> 1) & 3)) * 8;

  // A reg-staging map
  const int r0 = tid >> 2;
  const int c0log = (tid & 3) * 8;
  const int c0phys = ((tid & 3) ^ ((tid >> 3) & 3)) * 8;

  float4 aA[4], aB[4];

  auto loadA = [&](int kb, float4 (&d)[4]) {
    const int col = kb * 32 + c0log;
    const bool ok = col < DD;            // 784 % 8 == 0: whole octet in/out
    const int colc = ok ? col : 0;       // clamped: always issue 4 loads (vmcnt count fixed)
    const float* p0 = &X[(size_t)(bm + r0) * DD + colc];
    const float* p1 = &X[(size_t)(bm + r0 + 64) * DD + colc];
    d[0] = *(const float4*)p0; d[1] = *(const float4*)(p0 + 4);
    d[2] = *(const float4*)p1; d[3] = *(const float4*)(p1 + 4);
    if (!ok) {
      const float4 z = make_float4(0.f, 0.f, 0.f, 0.f);
      d[0] = z; d[1] = z; d[2] = z; d[3] = z;
    }
  };
  auto packA = [&](int bi, const float4 (&s_)[4]) {
    const unsigned ONE = 0x3C00u;        // f16 1.0
    auto pk = [&](float a, float b) {
      return (a != 0.f ? ONE : 0u) | (b != 0.f ? (ONE << 16) : 0u);
    };
    uint4 v0, v1;
    v0.x = pk(s_[0].x, s_[0].y); v0.y = pk(s_[0].z, s_[0].w);
    v0.z = pk(s_[1].x, s_[1].y); v0.w = pk(s_[1].z, s_[1].w);
    v1.x = pk(s_[2].x, s_[2].y); v1.y = pk(s_[2].z, s_[2].w);
    v1.z = pk(s_[3].x, s_[3].y); v1.w = pk(s_[3].z, s_[3].w);
    *(uint4*)&Asm[bi][r0 * 32 + c0phys] = v0;
    *(uint4*)&Asm[bi][(r0 + 64) * 32 + c0phys] = v1;
  };
  auto stageB = [&](int t) {
    const int k0 = t * 32, bi = t % 3;
    glds16(bsrc0 + k0, &Bsm[bi][0][(wid * 32) * 32]);
    glds16(bsrc1 + k0, &Bsm[bi][0][(wid * 32 + 16) * 32]);
    glds16(bsrc0 + pstr + k0, &Bsm[bi][1][(wid * 32) * 32]);
    glds16(bsrc1 + pstr + k0, &Bsm[bi][1][(wid * 32 + 16) * 32]);
  };
  auto compute = [&](int kb) {
    const int cb = kb & 1, b3 = kb % 3;
    f16x8 afr[4];
#pragma unroll
    for (int m = 0; m < 4; ++m)
      afr[m] = *(const f16x8*)&Asm[cb][(wr + m * 16 + l15) * 32 + rdsw];
#pragma unroll
    for (int s = 0; s < 2; ++s) {
      f16x8 bfr[4];
#pragma unroll
      for (int n = 0; n < 4; ++n)
        bfr[n] = *(const f16x8*)&Bsm[b3][s][(wc + n * 16 + l15) * 32 + rdsw];
#pragma unroll
      for (int m = 0; m < 4; ++m)
#pragma unroll
        for (int n = 0; n < 4; ++n)
          acc[s][m][n] = __builtin_amdgcn_mfma_f32_16x16x32_f16(afr[m], bfr[n], acc[s][m][n], 0, 0, 0);
    }
  };
  auto stepK = [&](int kb, const float4 (&pk_)[4], float4 (&ld_)[4]) {
    if (kb + 2 < nkb) stageB(kb + 2);
    compute(kb);
    __builtin_amdgcn_sched_barrier(0);
    // FIFO: [B(kb+1)x4, A(kb+1)x4, B(kb+2)x4] -> vmcnt(4) drains B,A(kb+1)
    if (kb + 2 < nkb) asm volatile("s_waitcnt vmcnt(4)" ::: "memory");
    else              asm volatile("s_waitcnt vmcnt(0)" ::: "memory");
    if (kb + 1 < nkb) packA((kb + 1) & 1, pk_);
    if (kb + 2 < nkb) loadA(kb + 2, ld_);
    asm volatile("s_waitcnt lgkmcnt(0)" ::: "memory");
    __builtin_amdgcn_sched_barrier(0);
    __builtin_amdgcn_s_barrier();
    __builtin_amdgcn_sched_barrier(0);
  };

  // prologue: A0->aA packed; A1->aB in flight; B0,B1 in flight
  loadA(0, aA);
  stageB(0); stageB(1);
  asm volatile("s_waitcnt vmcnt(8)" ::: "memory");   // [A0,B0,B1]=12 -> A0 landed
  packA(0, aA);
  loadA(1, aB);
  asm volatile("s_waitcnt vmcnt(8)" ::: "memory");   // [B0,B1,A1]=12 -> B0 landed
  asm volatile("s_waitcnt lgkmcnt(0)" ::: "memory");
  __builtin_amdgcn_s_barrier();
  __builtin_amdgcn_sched_barrier(0);

  for (int kb2 = 0; kb2 < nkb; kb2 += 2) {
    stepK(kb2, aB, aA);                      // pack A(odd) from aB, load A(even+2) into aA
    if (kb2 + 1 < nkb) stepK(kb2 + 1, aA, aB);
  }

#pragma unroll
  for (int m = 0; m < 4; ++m)
#pragma unroll
    for (int n = 0; n < 4; ++n) {
      const int col = bn + wc + n * 16 + l15;
      const float bv = bias[col];
#pragma unroll
      for (int r = 0; r < 4; ++r) {
        const int row = bm + wr + m * 16 + l4 * 4 + r;
        C[(size_t)row * HH + col] = fmaf(acc[1][m][n][r], INVMID, acc[0][m][n][r]) + bv;
      }
    }
}

// fp32 currents -> f16 spikes, 4 elems/thread
__global__ __launch_bounds__(256)
void lif_scan_h4(const float4* __restrict__ cur, uint2* __restrict__ spk,
                 int NE4, int nt) {
  const int tid = blockIdx.x * 256 + threadIdx.x;
  float4 mem = make_float4(0.f, 0.f, 0.f, 0.f);
  auto step1 = [](float& m, float c) {
    const float reset = (m > 1.0f) ? 1.0f : 0.0f;
    m = __fsub_rn(__fadd_rn(__fmul_rn(0.9f, m), c), reset);
    return (m > 1.0f);
  };
#pragma unroll 4
  for (int t = 0; t < nt; ++t) {
    const float4 c = cur[(size_t)t * NE4 + tid];
    unsigned s0 = step1(mem.x, c.x) ? 0x3C00u : 0u;
    unsigned s1 = step1(mem.y, c.y) ? 0x3C00u : 0u;
    unsigned s2 = step1(mem.z, c.z) ? 0x3C00u : 0u;
    unsigned s3 = step1(mem.w, c.w) ? 0x3C00u : 0u;
    uint2 o;
    o.x = s0 | (s1 << 16);
    o.y = s2 | (s3 << 16);
    spk[(size_t)t * NE4 + tid] = o;
  }
}

// Fused layer-2 GEMM + LIF scan: block = 16 b-rows x 64 d-cols, loops all T.
// W2 fragments (2 planes x 8 k-steps) live in REGISTERS for the whole kernel;
// spk1 t-slice (8 KB) glds-staged per t, triple-buffered, counted vmcnt.
// cur2 never touches HBM. Numerically identical to the unfused gemm+scan.
__global__ __launch_bounds__(256, 1)
void fused_l2(const unsigned short* __restrict__ spk1,   // [T][256][256] f16
              const unsigned short* __restrict__ W2s,    // 2 planes [832][256] f16
              const float* __restrict__ b2, float* __restrict__ out) {
  __shared__ unsigned short Asm[3][16 * 256];   // 3 x 8 KB
  const int tid = threadIdx.x, wid = tid >> 6, lane = tid & 63;
  const int l15 = lane & 15, l4 = lane >> 4;
  const int b0 = blockIdx.x * 16;
  const int d0 = blockIdx.y * 64;
  const int col = d0 + wid * 16 + l15;          // output d (within DPAD)
  const bool st = (col < DD);                   // wave-uniform (16-col groups)

  // W2 fragments: load once (16 dwordx4 per lane)
  f16x8 wfr[2][8];
#pragma unroll
  for (int s = 0; s < 2; ++s)
#pragma unroll
    for (int ks = 0; ks < 8; ++ks)
      wfr[s][ks] = *(const f16x8*)&W2s[(size_t)s * DPAD * HH + (size_t)col * HH + ks * 32 + l4 * 8];
  const float bv = st ? b2[col] : 0.f;

  // glds src (pre-swizzled): instr i: rows r = (wid*2+i)*2 + (lane>>5),
  // elem = ((lane&31)*8) ^ ((r&7)<<3)  [ushorts]
  const unsigned short* asrc[2];
#pragma unroll
  for (int i = 0; i < 2; ++i) {
    const int r = (wid * 2 + i) * 2 + (lane >> 5);
    const int e = ((lane & 31) * 8) ^ ((r & 7) << 3);
    asrc[i] = spk1 + (size_t)(b0 + r) * HH + e;
  }
  auto stageA = [&](int t) {
    const int bi = t % 3;
    const size_t toff = (size_t)t * (BB * HH);
    glds16(asrc[0] + toff, &Asm[bi][(wid * 2) * 512]);
    glds16(asrc[1] + toff, &Asm[bi][(wid * 2 + 1) * 512]);
  };

  f32x4 mem = (f32x4){0.f, 0.f, 0.f, 0.f};
  const size_t obase = (size_t)(b0 + l4 * 4) * DD + col;

  stageA(0); stageA(1);
  asm volatile("s_waitcnt vmcnt(2)" ::: "memory");   // [wfr x16, bv, g0 x2, g1 x2]: t=0 landed
  __builtin_amdgcn_s_barrier();
  __builtin_amdgcn_sched_barrier(0);

  for (int t = 0; t < TT; ++t) {
    if (t + 2 < TT) stageA(t + 2);
    const int bi = t % 3;
    f32x4 a0 = (f32x4){0.f, 0.f, 0.f, 0.f};
    f32x4 a1 = (f32x4){0.f, 0.f, 0.f, 0.f};
#pragma unroll
    for (int ks = 0; ks < 8; ++ks) {
      const int ro = l15 * 256 + ((ks * 32 + l4 * 8) ^ ((l15 & 7) << 3));
      const f16x8 afr = *(const f16x8*)&Asm[bi][ro];
      a0 = __builtin_amdgcn_mfma_f32_16x16x32_f16(afr, wfr[0][ks], a0, 0, 0, 0);
      a1 = __builtin_amdgcn_mfma_f32_16x16x32_f16(afr, wfr[1][ks], a1, 0, 0, 0);
    }
    if (st) {
#pragma unroll
      for (int r = 0; r < 4; ++r) {
        const float cur = fmaf(a1[r], INVMID, a0[r]) + bv;
        const float reset = (mem[r] > 1.0f) ? 1.0f : 0.0f;
        mem[r] = __fsub_rn(__fadd_rn(__fmul_rn(0.9f, mem[r]), cur), reset);
        out[(size_t)t * (BB * DD) + obase + (size_t)r * DD] = (mem[r] > 1.0f) ? 1.0f : 0.0f;
      }
    }
    __builtin_amdgcn_sched_barrier(0);
    // storing waves: FIFO [g(t+1)x2, st(t-1)x4, g(t+2)x2, st(t)x4] -> vmcnt(6)
    // padding waves (no stores): [g(t+1)x2, g(t+2)x2] -> vmcnt(2)
    if (t + 2 < TT) {
      if (st) asm volatile("s_waitcnt vmcnt(6)" ::: "memory");
      else    asm volatile("s_waitcnt vmcnt(2)" ::: "memory");
    } else if (t + 1 < TT) {
      if (st) asm volatile("s_waitcnt vmcnt(4)" ::: "memory");
      else    asm volatile("s_waitcnt vmcnt(0)" ::: "memory");
    }
    if (t + 1 < TT) {
      __builtin_amdgcn_s_barrier();
      __builtin_amdgcn_sched_barrier(0);
    }
  }
}

extern "C" void kernel_launch(void* const* d_in, const int* in_sizes, int n_in,
                              void* d_out, int out_size, void* d_ws, size_t ws_size,
                              hipStream_t stream) {
  const float* x  = (const float*)d_in[0];
  const float* W1 = (const float*)d_in[1];
  const float* b1 = (const float*)d_in[2];
  const float* W2 = (const float*)d_in[3];
  const float* b2 = (const float*)d_in[4];
  float* out = (float*)d_out;

  const size_t w1s_elems = (size_t)2 * HH * K1PAD;   // 409600
  const size_t w2s_elems = (size_t)2 * DPAD * HH;    // 425984
  unsigned short* W1s = (unsigned short*)d_ws;
  unsigned short* W2s = W1s + w1s_elems;
  float* cur1 = (float*)(W2s + w2s_elems);
  unsigned short* spk1 = (unsigned short*)(cur1 + (size_t)MM * HH);

  dim3 blk(256);

  split_w<<<dim3((HH * K1PAD + 255) / 256), blk, 0, stream>>>(W1, W1s, HH, DD, HH, K1PAD);
  split_w<<<dim3((DPAD * HH + 255) / 256), blk, 0, stream>>>(W2, W2s, DD, HH, DPAD, HH);

  // layer 1: cur1[M,256] = X @ W1^T + b1 (fp32 binary A converted in staging)
  gemm1<<<dim3(MM / 128, HH / 128), blk, 0, stream>>>(x, W1s, b1, cur1);

  // layer 1 LIF -> f16 spikes
  lif_scan_h4<<<dim3((BB * HH / 4) / 256), blk, 0, stream>>>(
      (const float4*)cur1, (uint2*)spk1, BB * HH / 4, TT);

  // layer 2 GEMM + LIF fused, writes spikes directly to d_out
  fused_l2<<<dim3(BB / 16, DPAD / 64), blk, 0, stream>>>(spk1, W2s, b2, out);
}